// Round 1
// baseline (739.947 us; speedup 1.0000x reference)
//
#include <hip/hip_runtime.h>
#include <stdint.h>

// ---- problem dims ----
#define KD 1024   // input dim
#define KH 4096   // hidden dim
#define KO 1024   // expert output dim
#define KE 8      // experts
#define KT 4096   // tokens (B*S = 2*2048)

typedef unsigned short u16;
typedef __bf16 bf16x8 __attribute__((ext_vector_type(8)));
typedef unsigned short ushort8 __attribute__((ext_vector_type(8)));
typedef float floatx4 __attribute__((ext_vector_type(4)));

__device__ __forceinline__ u16 f2bf(float f) {
  unsigned u = __float_as_uint(f);
  u += 0x7fffu + ((u >> 16) & 1u);   // round-to-nearest-even
  return (u16)(u >> 16);
}

// ---------------- x -> bf16 ----------------
__global__ void cvt_x_k(const float* __restrict__ x, u16* __restrict__ xbf) {
  int i = blockIdx.x * blockDim.x + threadIdx.x;   // one float4 per thread
  float4 v = ((const float4*)x)[i];
  union { u16 u[4]; uint2 v2; } o;
  o.u[0] = f2bf(v.x); o.u[1] = f2bf(v.y); o.u[2] = f2bf(v.z); o.u[3] = f2bf(v.w);
  ((uint2*)xbf)[i] = o.v2;
}

// ---------------- transpose + convert weights: in[E][R][C] f32 -> out[E][C][R] bf16 ----------------
__global__ void transpose_k(const float* __restrict__ in, u16* __restrict__ out,
                            int R, int C) {
  __shared__ float tile[32][33];
  const int e = blockIdx.z;
  const float* I = in + (size_t)e * R * C;
  u16* Oo = out + (size_t)e * R * C;
  const int c0 = blockIdx.x * 32, r0 = blockIdx.y * 32;
  const int tx = threadIdx.x, ty = threadIdx.y;   // (32, 8)
#pragma unroll
  for (int i = 0; i < 4; i++) {
    int r = r0 + ty + i * 8;
    tile[ty + i * 8][tx] = I[(size_t)r * C + c0 + tx];
  }
  __syncthreads();
#pragma unroll
  for (int i = 0; i < 4; i++) {
    int c = c0 + ty + i * 8;
    Oo[(size_t)c * R + r0 + tx] = f2bf(tile[tx][ty + i * 8]);
  }
}

// ---------------- router: logits, top-2, softmax, bucket ----------------
__global__ void router_k(const float* __restrict__ x, const float* __restrict__ Wr,
                         const float* __restrict__ br, int* __restrict__ cnt,
                         int* __restrict__ tok, float* __restrict__ gat) {
  const int t = blockIdx.x;
  const int lane = threadIdx.x;   // 64 threads = 1 wave
  const float* xr = x + (size_t)t * KD;
  double acc[KE];
#pragma unroll
  for (int e = 0; e < KE; e++) acc[e] = 0.0;
  for (int i = lane; i < KD; i += 64) {
    float xv = xr[i];
    const float* wr = Wr + i * KE;
#pragma unroll
    for (int e = 0; e < KE; e++) acc[e] += (double)xv * (double)wr[e];
  }
#pragma unroll
  for (int e = 0; e < KE; e++) {
#pragma unroll
    for (int m = 32; m > 0; m >>= 1) acc[e] += __shfl_xor(acc[e], m, 64);
  }
  if (lane == 0) {
    float l[KE];
#pragma unroll
    for (int e = 0; e < KE; e++) l[e] = (float)acc[e] + br[e];
    int i0 = 0;
#pragma unroll
    for (int e = 1; e < KE; e++) if (l[e] > l[i0]) i0 = e;
    int i1 = -1;
#pragma unroll
    for (int e = 0; e < KE; e++) {
      if (e == i0) continue;
      if (i1 < 0 || l[e] > l[i1]) i1 = e;
    }
    float g0 = 1.0f / (1.0f + expf(l[i1] - l[i0]));
    float g1 = 1.0f - g0;
    int p0 = atomicAdd(&cnt[i0], 1);
    tok[(i0 << 12) + p0] = t; gat[(i0 << 12) + p0] = g0;
    int p1 = atomicAdd(&cnt[i1], 1);
    tok[(i1 << 12) + p1] = t; gat[(i1 << 12) + p1] = g1;
  }
}

__global__ void offsets_k(const int* __restrict__ cnt, int* __restrict__ offs) {
  if (threadIdx.x == 0 && blockIdx.x == 0) {
    int s = 0;
#pragma unroll
    for (int e = 0; e < KE; e++) { offs[e] = s; s += cnt[e]; }
  }
}

// ---------------- GEMM1: h = relu(gather(x) @ W1 + b1) -> hbuf bf16 ----------------
// grid (H/128, 32, E), block 256. A gathered from xbf via tok list.
__global__ __launch_bounds__(256) void gemm1_k(
    const u16* __restrict__ xbf, const u16* __restrict__ w1t,
    const float* __restrict__ b1, const int* __restrict__ cnt,
    const int* __restrict__ offs, const int* __restrict__ tok,
    u16* __restrict__ hbuf) {
  const int e = blockIdx.z;
  const int me = cnt[e];
  const int m0 = blockIdx.y * 128;
  if (m0 >= me) return;
  const int n0 = blockIdx.x * 128;
  const int oe = offs[e];
  const int* tk = tok + (e << 12);

  __shared__ u16 As[128 * 32];
  __shared__ u16 Bs[128 * 32];

  const int tid = threadIdx.x;
  const int lane = tid & 63;
  const int w = tid >> 6;
  const int wm = w >> 1, wn = w & 1;

  // staging: 2 threads per row, 32B (16 elems) each
  const int srow = tid >> 1;
  const int scol = (tid & 1) << 4;
  const int arow = m0 + srow;
  const int atok = (arow < me) ? tk[arow] : 0;
  const u16* ap = xbf + ((size_t)atok << 10) + scol;
  const u16* bp = w1t + ((size_t)e << 22) + ((size_t)(n0 + srow) << 10) + scol;
  u16* asw = &As[srow * 32 + scol];
  u16* bsw = &Bs[srow * 32 + scol];

  floatx4 acc[4][4] = {};
  const int fr = lane & 15;
  const int kq = (lane >> 4) << 3;

  for (int kt = 0; kt < KD / 32; ++kt) {
    ushort8 a0 = *(const ushort8*)(ap + kt * 32);
    ushort8 a1 = *(const ushort8*)(ap + kt * 32 + 8);
    ushort8 b0 = *(const ushort8*)(bp + kt * 32);
    ushort8 b1v = *(const ushort8*)(bp + kt * 32 + 8);
    __syncthreads();
    *(ushort8*)asw = a0;
    *(ushort8*)(asw + 8) = a1;
    *(ushort8*)bsw = b0;
    *(ushort8*)(bsw + 8) = b1v;
    __syncthreads();
    bf16x8 af[4], bfr[4];
#pragma unroll
    for (int i = 0; i < 4; i++) {
      af[i]  = __builtin_bit_cast(bf16x8, *(const ushort8*)&As[(wm * 64 + i * 16 + fr) * 32 + kq]);
      bfr[i] = __builtin_bit_cast(bf16x8, *(const ushort8*)&Bs[(wn * 64 + i * 16 + fr) * 32 + kq]);
    }
#pragma unroll
    for (int mi = 0; mi < 4; mi++)
#pragma unroll
      for (int ni = 0; ni < 4; ni++)
        acc[mi][ni] = __builtin_amdgcn_mfma_f32_16x16x32_bf16(af[mi], bfr[ni], acc[mi][ni], 0, 0, 0);
  }

  // epilogue: +b1, relu, bf16 store to hbuf (C/D: col=lane&15, row=(lane>>4)*4+r)
  const int q = lane >> 4;
#pragma unroll
  for (int ni = 0; ni < 4; ni++) {
    const int gcol = n0 + wn * 64 + ni * 16 + fr;
    const float bb = b1[(e << 12) + gcol];
#pragma unroll
    for (int mi = 0; mi < 4; mi++) {
#pragma unroll
      for (int r = 0; r < 4; r++) {
        const int gr = m0 + wm * 64 + mi * 16 + q * 4 + r;
        if (gr < me) {
          float v = fmaxf(acc[mi][ni][r] + bb, 0.0f);
          hbuf[((size_t)(oe + gr) << 12) + gcol] = f2bf(v);
        }
      }
    }
  }
}

// ---------------- GEMM2: y = hbuf @ W2 + b2; out[t] += gate*y (atomic) ----------------
// grid (O/128, 32, E), block 256.
__global__ __launch_bounds__(256) void gemm2_k(
    const u16* __restrict__ hbuf, const u16* __restrict__ w2t,
    const float* __restrict__ b2, const int* __restrict__ cnt,
    const int* __restrict__ offs, const int* __restrict__ tok,
    const float* __restrict__ gat, float* __restrict__ out) {
  const int e = blockIdx.z;
  const int me = cnt[e];
  const int m0 = blockIdx.y * 128;
  if (m0 >= me) return;
  const int n0 = blockIdx.x * 128;
  const int oe = offs[e];
  const int* tk = tok + (e << 12);

  __shared__ u16 As[128 * 32];
  __shared__ u16 Bs[128 * 32];

  const int tid = threadIdx.x;
  const int lane = tid & 63;
  const int w = tid >> 6;
  const int wm = w >> 1, wn = w & 1;

  const int srow = tid >> 1;
  const int scol = (tid & 1) << 4;
  const int arow = m0 + srow;
  const int slot = oe + ((arow < me) ? arow : 0);   // clamp: stay in valid hbuf
  const u16* ap = hbuf + ((size_t)slot << 12) + scol;
  const u16* bp = w2t + ((size_t)e << 22) + ((size_t)(n0 + srow) << 12) + scol;
  u16* asw = &As[srow * 32 + scol];
  u16* bsw = &Bs[srow * 32 + scol];

  floatx4 acc[4][4] = {};
  const int fr = lane & 15;
  const int kq = (lane >> 4) << 3;

  for (int kt = 0; kt < KH / 32; ++kt) {
    ushort8 a0 = *(const ushort8*)(ap + kt * 32);
    ushort8 a1 = *(const ushort8*)(ap + kt * 32 + 8);
    ushort8 b0 = *(const ushort8*)(bp + kt * 32);
    ushort8 b1v = *(const ushort8*)(bp + kt * 32 + 8);
    __syncthreads();
    *(ushort8*)asw = a0;
    *(ushort8*)(asw + 8) = a1;
    *(ushort8*)bsw = b0;
    *(ushort8*)(bsw + 8) = b1v;
    __syncthreads();
    bf16x8 af[4], bfr[4];
#pragma unroll
    for (int i = 0; i < 4; i++) {
      af[i]  = __builtin_bit_cast(bf16x8, *(const ushort8*)&As[(wm * 64 + i * 16 + fr) * 32 + kq]);
      bfr[i] = __builtin_bit_cast(bf16x8, *(const ushort8*)&Bs[(wn * 64 + i * 16 + fr) * 32 + kq]);
    }
#pragma unroll
    for (int mi = 0; mi < 4; mi++)
#pragma unroll
      for (int ni = 0; ni < 4; ni++)
        acc[mi][ni] = __builtin_amdgcn_mfma_f32_16x16x32_bf16(af[mi], bfr[ni], acc[mi][ni], 0, 0, 0);
  }

  // epilogue: +b2, *gate, atomic scatter-add into out[token]
  const int q = lane >> 4;
  float bb[4];
#pragma unroll
  for (int ni = 0; ni < 4; ni++) bb[ni] = b2[(e << 10) + n0 + wn * 64 + ni * 16 + fr];
#pragma unroll
  for (int mi = 0; mi < 4; mi++) {
#pragma unroll
    for (int r = 0; r < 4; r++) {
      const int gr = m0 + wm * 64 + mi * 16 + q * 4 + r;
      if (gr < me) {
        const int tt = tk[gr];
        const float g = gat[(e << 12) + gr];
        float* orow = out + ((size_t)tt << 10);
#pragma unroll
        for (int ni = 0; ni < 4; ni++) {
          const int gcol = n0 + wn * 64 + ni * 16 + fr;
          atomicAdd(orow + gcol, (acc[mi][ni][r] + bb[ni]) * g);
        }
      }
    }
  }
}

extern "C" void kernel_launch(void* const* d_in, const int* in_sizes, int n_in,
                              void* d_out, int out_size, void* d_ws, size_t ws_size,
                              hipStream_t stream) {
  const float* x  = (const float*)d_in[0];
  const float* Wr = (const float*)d_in[1];
  const float* br = (const float*)d_in[2];
  const float* W1 = (const float*)d_in[3];
  const float* b1 = (const float*)d_in[4];
  const float* W2 = (const float*)d_in[5];
  const float* b2 = (const float*)d_in[6];
  float* out = (float*)d_out;

  char* ws = (char*)d_ws;
  size_t p = 0;
  auto alloc = [&](size_t bytes) {
    void* r = ws + p;
    p = (p + bytes + 255) & ~(size_t)255;
    return r;
  };
  int*   cnt  = (int*)alloc(KE * 4);
  int*   offs = (int*)alloc(KE * 4);
  int*   tok  = (int*)alloc((size_t)KE * KT * 4);
  float* gat  = (float*)alloc((size_t)KE * KT * 4);
  u16*   xbf  = (u16*)alloc((size_t)KT * KD * 2);
  u16*   w1t  = (u16*)alloc((size_t)KE * KD * KH * 2);
  u16*   w2t  = (u16*)alloc((size_t)KE * KH * KO * 2);
  u16*   hbuf = (u16*)alloc((size_t)2 * KT * KH * 2);

  hipMemsetAsync(out, 0, (size_t)KT * KO * 4, stream);
  hipMemsetAsync(cnt, 0, KE * 4, stream);

  cvt_x_k<<<(KT * KD / 4) / 256, 256, 0, stream>>>(x, xbf);
  transpose_k<<<dim3(KH / 32, KD / 32, KE), dim3(32, 8), 0, stream>>>(W1, w1t, KD, KH);
  transpose_k<<<dim3(KO / 32, KH / 32, KE), dim3(32, 8), 0, stream>>>(W2, w2t, KH, KO);
  router_k<<<KT, 64, 0, stream>>>(x, Wr, br, cnt, tok, gat);
  offsets_k<<<1, 64, 0, stream>>>(cnt, offs);
  gemm1_k<<<dim3(KH / 128, KT / 128, KE), 256, 0, stream>>>(xbf, w1t, b1, cnt, offs, tok, hbuf);
  gemm2_k<<<dim3(KO / 128, KT / 128, KE), 256, 0, stream>>>(hbuf, w2t, b2, cnt, offs, tok, gat, out);
}

// Round 3
// 620.430 us; speedup vs baseline: 1.1926x; 1.1926x over previous
//
#include <hip/hip_runtime.h>
#include <stdint.h>

// ---- problem dims ----
#define KD 1024   // input dim
#define KH 4096   // hidden dim
#define KO 1024   // expert output dim
#define KE 8      // experts
#define KT 4096   // tokens (B*S = 2*2048)

typedef unsigned short u16;
typedef __bf16 bf16x8 __attribute__((ext_vector_type(8)));
typedef unsigned short ushort8 __attribute__((ext_vector_type(8)));
typedef float floatx4 __attribute__((ext_vector_type(4)));

__device__ __forceinline__ u16 f2bf(float f) {
  unsigned u = __float_as_uint(f);
  u += 0x7fffu + ((u >> 16) & 1u);   // round-to-nearest-even
  return (u16)(u >> 16);
}

// direct global->LDS DMA, 16B per lane (HW dest = wave-uniform base + lane*16B)
__device__ __forceinline__ void glds16(const u16* g, u16* l) {
  __builtin_amdgcn_global_load_lds(
      (const __attribute__((address_space(1))) unsigned int*)(g),
      (__attribute__((address_space(3))) unsigned int*)(l), 16, 0, 0);
}

// ---------------- x -> bf16 ----------------
__global__ void cvt_x_k(const float* __restrict__ x, u16* __restrict__ xbf) {
  int i = blockIdx.x * blockDim.x + threadIdx.x;   // one float4 per thread
  float4 v = ((const float4*)x)[i];
  union { u16 u[4]; uint2 v2; } o;
  o.u[0] = f2bf(v.x); o.u[1] = f2bf(v.y); o.u[2] = f2bf(v.z); o.u[3] = f2bf(v.w);
  ((uint2*)xbf)[i] = o.v2;
}

// ---------------- transpose + convert weights: in[E][R][C] f32 -> out[E][C][R] bf16 ----------------
__global__ void transpose_k(const float* __restrict__ in, u16* __restrict__ out,
                            int R, int C) {
  __shared__ float tile[32][33];
  const int e = blockIdx.z;
  const float* I = in + (size_t)e * R * C;
  u16* Oo = out + (size_t)e * R * C;
  const int c0 = blockIdx.x * 32, r0 = blockIdx.y * 32;
  const int tx = threadIdx.x, ty = threadIdx.y;   // (32, 8)
#pragma unroll
  for (int i = 0; i < 4; i++) {
    int r = r0 + ty + i * 8;
    tile[ty + i * 8][tx] = I[(size_t)r * C + c0 + tx];
  }
  __syncthreads();
#pragma unroll
  for (int i = 0; i < 4; i++) {
    int c = c0 + ty + i * 8;
    Oo[(size_t)c * R + r0 + tx] = f2bf(tile[tx][ty + i * 8]);
  }
}

// ---------------- router: per-token top-2 + gates (NO atomics — deterministic) ----------------
__global__ void router_k(const float* __restrict__ x, const float* __restrict__ Wr,
                         const float* __restrict__ br, int* __restrict__ eidx,
                         float2* __restrict__ gpair) {
  const int t = blockIdx.x;
  const int lane = threadIdx.x;   // 64 threads = 1 wave
  const float* xr = x + (size_t)t * KD;
  double acc[KE];
#pragma unroll
  for (int e = 0; e < KE; e++) acc[e] = 0.0;
  for (int i = lane; i < KD; i += 64) {
    float xv = xr[i];
    const float* wr = Wr + i * KE;
#pragma unroll
    for (int e = 0; e < KE; e++) acc[e] += (double)xv * (double)wr[e];
  }
#pragma unroll
  for (int e = 0; e < KE; e++) {
#pragma unroll
    for (int m = 32; m > 0; m >>= 1) acc[e] += __shfl_xor(acc[e], m, 64);
  }
  if (lane == 0) {
    float l[KE];
#pragma unroll
    for (int e = 0; e < KE; e++) l[e] = (float)acc[e] + br[e];
    int i0 = 0;
#pragma unroll
    for (int e = 1; e < KE; e++) if (l[e] > l[i0]) i0 = e;
    int i1 = -1;
#pragma unroll
    for (int e = 0; e < KE; e++) {
      if (e == i0) continue;
      if (i1 < 0 || l[e] > l[i1]) i1 = e;
    }
    float g0 = 1.0f / (1.0f + expf(l[i1] - l[i0]));
    eidx[t] = i0 | (i1 << 4);
    gpair[t] = make_float2(g0, 1.0f - g0);
  }
}

// ---------------- bucket: deterministic per-expert compaction (ascending token order) ----------------
__global__ __launch_bounds__(256) void bucket_k(const int* __restrict__ eidx,
                                                const float2* __restrict__ gp,
                                                int* __restrict__ cnt,
                                                int* __restrict__ tok,
                                                float* __restrict__ gat) {
  const int e = blockIdx.x;
  const int tid = threadIdx.x;       // 256 threads, 16 tokens each
  const int t0 = tid * 16;
  int f[16]; float g[16]; int c = 0;
#pragma unroll
  for (int j = 0; j < 16; j++) {
    int pk = eidx[t0 + j];
    float2 gg = gp[t0 + j];
    int h0 = ((pk & 15) == e);
    int h1 = (((pk >> 4) & 15) == e);
    f[j] = h0 | h1;
    g[j] = h0 ? gg.x : gg.y;
    c += f[j];
  }
  __shared__ int sc[256];
  sc[tid] = c;
  __syncthreads();
  // Hillis-Steele inclusive scan (read phase / barrier / write phase)
  for (int d = 1; d < 256; d <<= 1) {
    int add = (tid >= d) ? sc[tid - d] : 0;
    __syncthreads();
    sc[tid] += add;
    __syncthreads();
  }
  int base = sc[tid] - c;            // exclusive prefix
  if (tid == 0) cnt[e] = sc[255];
#pragma unroll
  for (int j = 0; j < 16; j++) {
    if (f[j]) {
      tok[(e << 12) + base] = t0 + j;
      gat[(e << 12) + base] = g[j];
      base++;
    }
  }
}

__global__ void offsets_k(const int* __restrict__ cnt, int* __restrict__ offs) {
  if (threadIdx.x == 0 && blockIdx.x == 0) {
    int s = 0;
#pragma unroll
    for (int e = 0; e < KE; e++) { offs[e] = s; s += cnt[e]; }
  }
}

// ---------------- GEMM1: h = relu(gather(x) @ W1 + b1) -> hbuf bf16 ----------------
__global__ __launch_bounds__(256) void gemm1_k(
    const u16* __restrict__ xbf, const u16* __restrict__ w1t,
    const float* __restrict__ b1, const int* __restrict__ cnt,
    const int* __restrict__ offs, const int* __restrict__ tok,
    u16* __restrict__ hbuf) {
  const int e = blockIdx.z;
  const int me = cnt[e];
  const int m0 = blockIdx.y * 128;
  if (m0 >= me) return;
  const int n0 = blockIdx.x * 128;
  const int oe = offs[e];
  const int* tk = tok + (e << 12);

  __shared__ u16 As[128 * 32];
  __shared__ u16 Bs[128 * 32];

  const int tid = threadIdx.x;
  const int lane = tid & 63;
  const int w = tid >> 6;
  const int wm = w >> 1, wn = w & 1;

  const int rr = lane >> 2;            // 0..15
  const int cc = (lane & 3) << 3;      // 0/8/16/24
  const int ar0 = m0 + w * 32 + rr;
  const int ar1 = ar0 + 16;
  const int ta0 = (ar0 < me) ? tk[ar0] : 0;
  const int ta1 = (ar1 < me) ? tk[ar1] : 0;
  const u16* ga0 = xbf + ((size_t)ta0 << 10) + cc;
  const u16* ga1 = xbf + ((size_t)ta1 << 10) + cc;
  const int br0 = n0 + w * 32 + rr;
  const u16* gb0 = w1t + ((size_t)e << 22) + ((size_t)br0 << 10) + cc;
  const u16* gb1 = gb0 + (16 << 10);
  u16* la0 = &As[(w * 32) * 32] + lane * 8;
  u16* la1 = la0 + 512;
  u16* lb0 = &Bs[(w * 32) * 32] + lane * 8;
  u16* lb1 = lb0 + 512;

  floatx4 acc[4][4] = {};
  const int fr = lane & 15;
  const int kq = (lane >> 4) << 3;

  for (int kt = 0; kt < KD / 32; ++kt) {
    __syncthreads();
    glds16(ga0 + kt * 32, la0);
    glds16(ga1 + kt * 32, la1);
    glds16(gb0 + kt * 32, lb0);
    glds16(gb1 + kt * 32, lb1);
    __builtin_amdgcn_s_waitcnt(0);   // insurance: DMA landed before barrier
    __syncthreads();
    bf16x8 af[4], bfr[4];
#pragma unroll
    for (int i = 0; i < 4; i++) {
      af[i]  = __builtin_bit_cast(bf16x8, *(const ushort8*)&As[(wm * 64 + i * 16 + fr) * 32 + kq]);
      bfr[i] = __builtin_bit_cast(bf16x8, *(const ushort8*)&Bs[(wn * 64 + i * 16 + fr) * 32 + kq]);
    }
#pragma unroll
    for (int mi = 0; mi < 4; mi++)
#pragma unroll
      for (int ni = 0; ni < 4; ni++)
        acc[mi][ni] = __builtin_amdgcn_mfma_f32_16x16x32_bf16(af[mi], bfr[ni], acc[mi][ni], 0, 0, 0);
  }

  const int q = lane >> 4;
#pragma unroll
  for (int ni = 0; ni < 4; ni++) {
    const int gcol = n0 + wn * 64 + ni * 16 + fr;
    const float bb = b1[(e << 12) + gcol];
#pragma unroll
    for (int mi = 0; mi < 4; mi++) {
#pragma unroll
      for (int r = 0; r < 4; r++) {
        const int gr = m0 + wm * 64 + mi * 16 + q * 4 + r;
        if (gr < me) {
          float v = fmaxf(acc[mi][ni][r] + bb, 0.0f);
          hbuf[((size_t)(oe + gr) << 12) + gcol] = f2bf(v);
        }
      }
    }
  }
}

// ---------------- GEMM2: y = hbuf @ W2 + b2; out[t] += gate*y (atomic); split-K=2 ----------------
__global__ __launch_bounds__(256) void gemm2_k(
    const u16* __restrict__ hbuf, const u16* __restrict__ w2t,
    const float* __restrict__ b2, const int* __restrict__ cnt,
    const int* __restrict__ offs, const int* __restrict__ tok,
    const float* __restrict__ gat, float* __restrict__ out) {
  const int e = blockIdx.z;
  const int me = cnt[e];
  const int m0 = blockIdx.y * 128;
  if (m0 >= me) return;
  const int ks = blockIdx.x & 1;
  const int n0 = (blockIdx.x >> 1) * 128;
  const int k0 = ks * (KH / 2);
  const int oe = offs[e];
  const int* tk = tok + (e << 12);

  __shared__ u16 As[128 * 32];
  __shared__ u16 Bs[128 * 32];

  const int tid = threadIdx.x;
  const int lane = tid & 63;
  const int w = tid >> 6;
  const int wm = w >> 1, wn = w & 1;

  const int rr = lane >> 2;
  const int cc = (lane & 3) << 3;
  const int ar0 = m0 + w * 32 + rr;
  const int ar1 = ar0 + 16;
  const int sl0 = oe + ((ar0 < me) ? ar0 : 0);
  const int sl1 = oe + ((ar1 < me) ? ar1 : 0);
  const u16* ga0 = hbuf + ((size_t)sl0 << 12) + k0 + cc;
  const u16* ga1 = hbuf + ((size_t)sl1 << 12) + k0 + cc;
  const int br0 = n0 + w * 32 + rr;
  const u16* gb0 = w2t + ((size_t)e << 22) + ((size_t)br0 << 12) + k0 + cc;
  const u16* gb1 = gb0 + (16 << 12);
  u16* la0 = &As[(w * 32) * 32] + lane * 8;
  u16* la1 = la0 + 512;
  u16* lb0 = &Bs[(w * 32) * 32] + lane * 8;
  u16* lb1 = lb0 + 512;

  floatx4 acc[4][4] = {};
  const int fr = lane & 15;
  const int kq = (lane >> 4) << 3;

  for (int kt = 0; kt < KH / 2 / 32; ++kt) {
    __syncthreads();
    glds16(ga0 + kt * 32, la0);
    glds16(ga1 + kt * 32, la1);
    glds16(gb0 + kt * 32, lb0);
    glds16(gb1 + kt * 32, lb1);
    __builtin_amdgcn_s_waitcnt(0);   // insurance: DMA landed before barrier
    __syncthreads();
    bf16x8 af[4], bfr[4];
#pragma unroll
    for (int i = 0; i < 4; i++) {
      af[i]  = __builtin_bit_cast(bf16x8, *(const ushort8*)&As[(wm * 64 + i * 16 + fr) * 32 + kq]);
      bfr[i] = __builtin_bit_cast(bf16x8, *(const ushort8*)&Bs[(wn * 64 + i * 16 + fr) * 32 + kq]);
    }
#pragma unroll
    for (int mi = 0; mi < 4; mi++)
#pragma unroll
      for (int ni = 0; ni < 4; ni++)
        acc[mi][ni] = __builtin_amdgcn_mfma_f32_16x16x32_bf16(af[mi], bfr[ni], acc[mi][ni], 0, 0, 0);
  }

  const int q = lane >> 4;
  float bb[4];
#pragma unroll
  for (int ni = 0; ni < 4; ni++)
    bb[ni] = (ks == 0) ? b2[(e << 10) + n0 + wn * 64 + ni * 16 + fr] : 0.0f;
#pragma unroll
  for (int mi = 0; mi < 4; mi++) {
#pragma unroll
    for (int r = 0; r < 4; r++) {
      const int gr = m0 + wm * 64 + mi * 16 + q * 4 + r;
      if (gr < me) {
        const int tt = tk[gr];
        const float g = gat[(e << 12) + gr];
        float* orow = out + ((size_t)tt << 10);
#pragma unroll
        for (int ni = 0; ni < 4; ni++) {
          const int gcol = n0 + wn * 64 + ni * 16 + fr;
          atomicAdd(orow + gcol, (acc[mi][ni][r] + bb[ni]) * g);
        }
      }
    }
  }
}

extern "C" void kernel_launch(void* const* d_in, const int* in_sizes, int n_in,
                              void* d_out, int out_size, void* d_ws, size_t ws_size,
                              hipStream_t stream) {
  const float* x  = (const float*)d_in[0];
  const float* Wr = (const float*)d_in[1];
  const float* br = (const float*)d_in[2];
  const float* W1 = (const float*)d_in[3];
  const float* b1 = (const float*)d_in[4];
  const float* W2 = (const float*)d_in[5];
  const float* b2 = (const float*)d_in[6];
  float* out = (float*)d_out;

  char* ws = (char*)d_ws;
  size_t p = 0;
  auto alloc = [&](size_t bytes) {
    void* r = ws + p;
    p = (p + bytes + 255) & ~(size_t)255;
    return r;
  };
  int*    cnt   = (int*)alloc(KE * 4);
  int*    offs  = (int*)alloc(KE * 4);
  int*    eidx  = (int*)alloc((size_t)KT * 4);
  float2* gpair = (float2*)alloc((size_t)KT * 8);
  int*    tok   = (int*)alloc((size_t)KE * KT * 4);
  float*  gat   = (float*)alloc((size_t)KE * KT * 4);
  u16*    xbf   = (u16*)alloc((size_t)KT * KD * 2);
  u16*    w1t   = (u16*)alloc((size_t)KE * KD * KH * 2);
  u16*    w2t   = (u16*)alloc((size_t)KE * KH * KO * 2);
  u16*    hbuf  = (u16*)alloc((size_t)2 * KT * KH * 2);

  hipMemsetAsync(out, 0, (size_t)KT * KO * 4, stream);

  cvt_x_k<<<(KT * KD / 4) / 256, 256, 0, stream>>>(x, xbf);
  transpose_k<<<dim3(KH / 32, KD / 32, KE), dim3(32, 8), 0, stream>>>(W1, w1t, KD, KH);
  transpose_k<<<dim3(KO / 32, KH / 32, KE), dim3(32, 8), 0, stream>>>(W2, w2t, KH, KO);
  router_k<<<KT, 64, 0, stream>>>(x, Wr, br, eidx, gpair);
  bucket_k<<<KE, 256, 0, stream>>>(eidx, gpair, cnt, tok, gat);
  offsets_k<<<1, 64, 0, stream>>>(cnt, offs);
  gemm1_k<<<dim3(KH / 128, KT / 128, KE), 256, 0, stream>>>(xbf, w1t, b1, cnt, offs, tok, hbuf);
  gemm2_k<<<dim3(2 * KO / 128, KT / 128, KE), 256, 0, stream>>>(hbuf, w2t, b2, cnt, offs, tok, gat, out);
}

// Round 4
// 608.383 us; speedup vs baseline: 1.2163x; 1.0198x over previous
//
#include <hip/hip_runtime.h>
#include <stdint.h>

// ---- problem dims ----
#define KD 1024   // input dim
#define KH 4096   // hidden dim
#define KO 1024   // expert output dim
#define KE 8      // experts
#define KT 4096   // tokens (B*S = 2*2048)

typedef unsigned short u16;
typedef __bf16 bf16x8 __attribute__((ext_vector_type(8)));
typedef unsigned short ushort8 __attribute__((ext_vector_type(8)));
typedef float floatx4 __attribute__((ext_vector_type(4)));

__device__ __forceinline__ u16 f2bf(float f) {
  unsigned u = __float_as_uint(f);
  u += 0x7fffu + ((u >> 16) & 1u);   // round-to-nearest-even
  return (u16)(u >> 16);
}

// direct global->LDS DMA, 16B per lane (HW dest = wave-uniform base + lane*16B)
__device__ __forceinline__ void glds16(const u16* g, u16* l) {
  __builtin_amdgcn_global_load_lds(
      (const __attribute__((address_space(1))) unsigned int*)(g),
      (__attribute__((address_space(3))) unsigned int*)(l), 16, 0, 0);
}

// ---------------- x -> bf16 ----------------
__global__ void cvt_x_k(const float* __restrict__ x, u16* __restrict__ xbf) {
  int i = blockIdx.x * blockDim.x + threadIdx.x;   // one float4 per thread
  float4 v = ((const float4*)x)[i];
  union { u16 u[4]; uint2 v2; } o;
  o.u[0] = f2bf(v.x); o.u[1] = f2bf(v.y); o.u[2] = f2bf(v.z); o.u[3] = f2bf(v.w);
  ((uint2*)xbf)[i] = o.v2;
}

// ------- transpose + convert: in[E][R][C] f32 -> out[E][C][R] bf16, 64x64 tiles -------
__global__ __launch_bounds__(256) void transpose_k(const float* __restrict__ in,
                                                   u16* __restrict__ out, int R, int C) {
  __shared__ float tile[64][65];
  const int e = blockIdx.z;
  const float* I = in + (size_t)e * R * C;
  u16* Oo = out + (size_t)e * R * C;
  const int c0 = blockIdx.x * 64, r0 = blockIdx.y * 64;
  const int t = threadIdx.x;
  const int rr = t >> 4;          // 0..15
  const int c4 = (t & 15) << 2;   // 0..60 step 4
#pragma unroll
  for (int j = 0; j < 4; j++) {
    int r = rr + j * 16;
    float4 v = *(const float4*)&I[(size_t)(r0 + r) * C + c0 + c4];
    tile[r][c4] = v.x; tile[r][c4 + 1] = v.y; tile[r][c4 + 2] = v.z; tile[r][c4 + 3] = v.w;
  }
  __syncthreads();
  const int cc = t >> 3;          // 0..31
  const int rb = (t & 7) << 3;    // 0..56 step 8
#pragma unroll
  for (int j = 0; j < 2; j++) {
    int c = cc + j * 32;
    ushort8 o;
#pragma unroll
    for (int k = 0; k < 8; k++) o[k] = f2bf(tile[rb + k][c]);
    *(ushort8*)&Oo[(size_t)(c0 + c) * R + r0 + rb] = o;
  }
}

// ---------------- router: per-token top-2 + gates (deterministic) ----------------
__global__ void router_k(const float* __restrict__ x, const float* __restrict__ Wr,
                         const float* __restrict__ br, int* __restrict__ eidx,
                         float2* __restrict__ gpair) {
  const int t = blockIdx.x;
  const int lane = threadIdx.x;   // 64 threads = 1 wave
  const float* xr = x + (size_t)t * KD;
  double acc[KE];
#pragma unroll
  for (int e = 0; e < KE; e++) acc[e] = 0.0;
  for (int i = lane; i < KD; i += 64) {
    float xv = xr[i];
    const float* wr = Wr + i * KE;
#pragma unroll
    for (int e = 0; e < KE; e++) acc[e] += (double)xv * (double)wr[e];
  }
#pragma unroll
  for (int e = 0; e < KE; e++) {
#pragma unroll
    for (int m = 32; m > 0; m >>= 1) acc[e] += __shfl_xor(acc[e], m, 64);
  }
  if (lane == 0) {
    float l[KE];
#pragma unroll
    for (int e = 0; e < KE; e++) l[e] = (float)acc[e] + br[e];
    int i0 = 0;
#pragma unroll
    for (int e = 1; e < KE; e++) if (l[e] > l[i0]) i0 = e;
    int i1 = -1;
#pragma unroll
    for (int e = 0; e < KE; e++) {
      if (e == i0) continue;
      if (i1 < 0 || l[e] > l[i1]) i1 = e;
    }
    float g0 = 1.0f / (1.0f + expf(l[i1] - l[i0]));
    eidx[t] = i0 | (i1 << 4);
    gpair[t] = make_float2(g0, 1.0f - g0);
  }
}

// ------- bucket: deterministic per-expert compaction; pos[2t+rank] = slot-within-expert -------
__global__ __launch_bounds__(256) void bucket_k(const int* __restrict__ eidx,
                                                int* __restrict__ cnt,
                                                int* __restrict__ tok,
                                                int* __restrict__ pos) {
  const int e = blockIdx.x;
  const int tid = threadIdx.x;       // 256 threads, 16 tokens each
  const int t0 = tid * 16;
  int f[16]; int c = 0;
#pragma unroll
  for (int j = 0; j < 16; j++) {
    int pk = eidx[t0 + j];
    int h0 = ((pk & 15) == e);
    int h1 = (((pk >> 4) & 15) == e);
    f[j] = h0 ? 1 : (h1 ? 2 : 0);    // 0=absent, 1=rank0, 2=rank1
    c += (f[j] != 0);
  }
  __shared__ int sc[256];
  sc[tid] = c;
  __syncthreads();
  for (int d = 1; d < 256; d <<= 1) {
    int add = (tid >= d) ? sc[tid - d] : 0;
    __syncthreads();
    sc[tid] += add;
    __syncthreads();
  }
  int base = sc[tid] - c;            // exclusive prefix
  if (tid == 0) cnt[e] = sc[255];
#pragma unroll
  for (int j = 0; j < 16; j++) {
    if (f[j]) {
      tok[(e << 12) + base] = t0 + j;
      pos[2 * (t0 + j) + (f[j] - 1)] = base;
      base++;
    }
  }
}

__global__ void offsets_k(const int* __restrict__ cnt, int* __restrict__ offs) {
  if (threadIdx.x == 0 && blockIdx.x == 0) {
    int s = 0;
#pragma unroll
    for (int e = 0; e < KE; e++) { offs[e] = s; s += cnt[e]; }
  }
}

// ---------------- GEMM1: h = relu(gather(x) @ W1 + b1) -> hbuf bf16. BK=64 (2 panels) ----------------
__global__ __launch_bounds__(256) void gemm1_k(
    const u16* __restrict__ xbf, const u16* __restrict__ w1t,
    const float* __restrict__ b1, const int* __restrict__ cnt,
    const int* __restrict__ offs, const int* __restrict__ tok,
    u16* __restrict__ hbuf) {
  const int e = blockIdx.z;
  const int me = cnt[e];
  const int m0 = blockIdx.y * 128;
  if (m0 >= me) return;
  const int n0 = blockIdx.x * 128;
  const int oe = offs[e];
  const int* tk = tok + (e << 12);

  __shared__ u16 As[2 * 128 * 32];   // [panel][row][32]
  __shared__ u16 Bs[2 * 128 * 32];

  const int tid = threadIdx.x;
  const int lane = tid & 63;
  const int w = tid >> 6;
  const int wm = w >> 1, wn = w & 1;

  const int rr = lane >> 2;            // 0..15
  const int cc = (lane & 3) << 3;      // 0/8/16/24
  const int ar0 = m0 + w * 32 + rr;
  const int ar1 = ar0 + 16;
  const int ta0 = (ar0 < me) ? tk[ar0] : 0;
  const int ta1 = (ar1 < me) ? tk[ar1] : 0;
  const u16* ga0 = xbf + ((size_t)ta0 << 10) + cc;
  const u16* ga1 = xbf + ((size_t)ta1 << 10) + cc;
  const int br0 = n0 + w * 32 + rr;
  const u16* gb0 = w1t + ((size_t)e << 22) + ((size_t)br0 << 10) + cc;
  const u16* gb1 = gb0 + (16 << 10);
  // LDS dests (wave-uniform base + lane*16B): panel p, row-seg s
  u16* la00 = &As[w * 1024] + lane * 8;          // p0 s0
  u16* la01 = la00 + 512;                        // p0 s1
  u16* la10 = la00 + 4096;                       // p1 s0
  u16* la11 = la00 + 4096 + 512;                 // p1 s1
  u16* lb00 = &Bs[w * 1024] + lane * 8;
  u16* lb01 = lb00 + 512;
  u16* lb10 = lb00 + 4096;
  u16* lb11 = lb00 + 4096 + 512;

  floatx4 acc[4][4] = {};
  const int fr = lane & 15;
  const int kq = (lane >> 4) << 3;

  for (int kt = 0; kt < KD / 64; ++kt) {
    const int k64 = kt * 64;
    __syncthreads();
    glds16(ga0 + k64,      la00);
    glds16(ga1 + k64,      la01);
    glds16(ga0 + k64 + 32, la10);
    glds16(ga1 + k64 + 32, la11);
    glds16(gb0 + k64,      lb00);
    glds16(gb1 + k64,      lb01);
    glds16(gb0 + k64 + 32, lb10);
    glds16(gb1 + k64 + 32, lb11);
    __builtin_amdgcn_s_waitcnt(0);   // DMA landed before barrier
    __syncthreads();
#pragma unroll
    for (int p = 0; p < 2; p++) {
      bf16x8 af[4], bfr[4];
#pragma unroll
      for (int i = 0; i < 4; i++) {
        af[i]  = __builtin_bit_cast(bf16x8, *(const ushort8*)&As[p * 4096 + (wm * 64 + i * 16 + fr) * 32 + kq]);
        bfr[i] = __builtin_bit_cast(bf16x8, *(const ushort8*)&Bs[p * 4096 + (wn * 64 + i * 16 + fr) * 32 + kq]);
      }
#pragma unroll
      for (int mi = 0; mi < 4; mi++)
#pragma unroll
        for (int ni = 0; ni < 4; ni++)
          acc[mi][ni] = __builtin_amdgcn_mfma_f32_16x16x32_bf16(af[mi], bfr[ni], acc[mi][ni], 0, 0, 0);
    }
  }

  const int q = lane >> 4;
#pragma unroll
  for (int ni = 0; ni < 4; ni++) {
    const int gcol = n0 + wn * 64 + ni * 16 + fr;
    const float bb = b1[(e << 12) + gcol];
#pragma unroll
    for (int mi = 0; mi < 4; mi++) {
#pragma unroll
      for (int r = 0; r < 4; r++) {
        const int gr = m0 + wm * 64 + mi * 16 + q * 4 + r;
        if (gr < me) {
          float v = fmaxf(acc[mi][ni][r] + bb, 0.0f);
          hbuf[((size_t)(oe + gr) << 12) + gcol] = f2bf(v);
        }
      }
    }
  }
}

// ------- GEMM2: y[ks][slot][:] = hbuf @ W2 (raw, no bias/gate). BK=64, split-K=2, no atomics -------
__global__ __launch_bounds__(256) void gemm2_k(
    const u16* __restrict__ hbuf, const u16* __restrict__ w2t,
    const int* __restrict__ cnt, const int* __restrict__ offs,
    float* __restrict__ y) {
  const int e = blockIdx.z;
  const int me = cnt[e];
  const int m0 = blockIdx.y * 128;
  if (m0 >= me) return;
  const int ks = blockIdx.x & 1;
  const int n0 = (blockIdx.x >> 1) * 128;
  const int k0 = ks * (KH / 2);
  const int oe = offs[e];

  __shared__ u16 As[2 * 128 * 32];
  __shared__ u16 Bs[2 * 128 * 32];

  const int tid = threadIdx.x;
  const int lane = tid & 63;
  const int w = tid >> 6;
  const int wm = w >> 1, wn = w & 1;

  const int rr = lane >> 2;
  const int cc = (lane & 3) << 3;
  const int ar0 = m0 + w * 32 + rr;
  const int ar1 = ar0 + 16;
  const int sl0 = oe + ((ar0 < me) ? ar0 : 0);
  const int sl1 = oe + ((ar1 < me) ? ar1 : 0);
  const u16* ga0 = hbuf + ((size_t)sl0 << 12) + k0 + cc;
  const u16* ga1 = hbuf + ((size_t)sl1 << 12) + k0 + cc;
  const int br0 = n0 + w * 32 + rr;
  const u16* gb0 = w2t + ((size_t)e << 22) + ((size_t)br0 << 12) + k0 + cc;
  const u16* gb1 = gb0 + (16 << 12);
  u16* la00 = &As[w * 1024] + lane * 8;
  u16* la01 = la00 + 512;
  u16* la10 = la00 + 4096;
  u16* la11 = la00 + 4096 + 512;
  u16* lb00 = &Bs[w * 1024] + lane * 8;
  u16* lb01 = lb00 + 512;
  u16* lb10 = lb00 + 4096;
  u16* lb11 = lb00 + 4096 + 512;

  floatx4 acc[4][4] = {};
  const int fr = lane & 15;
  const int kq = (lane >> 4) << 3;

  for (int kt = 0; kt < KH / 2 / 64; ++kt) {
    const int k64 = kt * 64;
    __syncthreads();
    glds16(ga0 + k64,      la00);
    glds16(ga1 + k64,      la01);
    glds16(ga0 + k64 + 32, la10);
    glds16(ga1 + k64 + 32, la11);
    glds16(gb0 + k64,      lb00);
    glds16(gb1 + k64,      lb01);
    glds16(gb0 + k64 + 32, lb10);
    glds16(gb1 + k64 + 32, lb11);
    __builtin_amdgcn_s_waitcnt(0);
    __syncthreads();
#pragma unroll
    for (int p = 0; p < 2; p++) {
      bf16x8 af[4], bfr[4];
#pragma unroll
      for (int i = 0; i < 4; i++) {
        af[i]  = __builtin_bit_cast(bf16x8, *(const ushort8*)&As[p * 4096 + (wm * 64 + i * 16 + fr) * 32 + kq]);
        bfr[i] = __builtin_bit_cast(bf16x8, *(const ushort8*)&Bs[p * 4096 + (wn * 64 + i * 16 + fr) * 32 + kq]);
      }
#pragma unroll
      for (int mi = 0; mi < 4; mi++)
#pragma unroll
        for (int ni = 0; ni < 4; ni++)
          acc[mi][ni] = __builtin_amdgcn_mfma_f32_16x16x32_bf16(af[mi], bfr[ni], acc[mi][ni], 0, 0, 0);
    }
  }

  // epilogue: raw coalesced stores into y[ks][slot][col]
  const int q = lane >> 4;
  float* yk = y + ((size_t)ks << 23);   // 8192*1024 = 1<<23
#pragma unroll
  for (int mi = 0; mi < 4; mi++) {
#pragma unroll
    for (int r = 0; r < 4; r++) {
      const int gr = m0 + wm * 64 + mi * 16 + q * 4 + r;
      if (gr < me) {
        float* yrow = yk + ((size_t)(oe + gr) << 10);
#pragma unroll
        for (int ni = 0; ni < 4; ni++)
          yrow[n0 + wn * 64 + ni * 16 + fr] = acc[mi][ni][r];
      }
    }
  }
}

// ------- combine: out[t] = sum_r g_r * (y0[s_r] + y1[s_r] + b2[e_r]) -------
__global__ __launch_bounds__(256) void combine_k(
    const float* __restrict__ y, const int* __restrict__ eidx,
    const float2* __restrict__ gp, const int* __restrict__ offs,
    const int* __restrict__ pos, const float* __restrict__ b2,
    float* __restrict__ out) {
  const int t = blockIdx.x;
  const int c4 = threadIdx.x << 2;
  const int pk = eidx[t];
  const int e0 = pk & 15, e1 = (pk >> 4) & 15;
  const float2 g = gp[t];
  const int s0 = offs[e0] + pos[2 * t];
  const int s1 = offs[e1] + pos[2 * t + 1];
  float4 a0 = *(const float4*)(y + ((size_t)s0 << 10) + c4);
  float4 a1 = *(const float4*)(y + (1ull << 23) + ((size_t)s0 << 10) + c4);
  float4 c0 = *(const float4*)(y + ((size_t)s1 << 10) + c4);
  float4 c1 = *(const float4*)(y + (1ull << 23) + ((size_t)s1 << 10) + c4);
  float4 ba = *(const float4*)(b2 + (e0 << 10) + c4);
  float4 bc = *(const float4*)(b2 + (e1 << 10) + c4);
  float4 o;
  o.x = g.x * (a0.x + a1.x + ba.x) + g.y * (c0.x + c1.x + bc.x);
  o.y = g.x * (a0.y + a1.y + ba.y) + g.y * (c0.y + c1.y + bc.y);
  o.z = g.x * (a0.z + a1.z + ba.z) + g.y * (c0.z + c1.z + bc.z);
  o.w = g.x * (a0.w + a1.w + ba.w) + g.y * (c0.w + c1.w + bc.w);
  *(float4*)(out + ((size_t)t << 10) + c4) = o;
}

extern "C" void kernel_launch(void* const* d_in, const int* in_sizes, int n_in,
                              void* d_out, int out_size, void* d_ws, size_t ws_size,
                              hipStream_t stream) {
  const float* x  = (const float*)d_in[0];
  const float* Wr = (const float*)d_in[1];
  const float* br = (const float*)d_in[2];
  const float* W1 = (const float*)d_in[3];
  const float* b1 = (const float*)d_in[4];
  const float* W2 = (const float*)d_in[5];
  const float* b2 = (const float*)d_in[6];
  float* out = (float*)d_out;

  char* ws = (char*)d_ws;
  size_t p = 0;
  auto alloc = [&](size_t bytes) {
    void* r = ws + p;
    p = (p + bytes + 255) & ~(size_t)255;
    return r;
  };
  int*    cnt   = (int*)alloc(KE * 4);
  int*    offs  = (int*)alloc(KE * 4);
  int*    eidx  = (int*)alloc((size_t)KT * 4);
  float2* gpair = (float2*)alloc((size_t)KT * 8);
  int*    pos   = (int*)alloc((size_t)2 * KT * 4);
  int*    tok   = (int*)alloc((size_t)KE * KT * 4);
  u16*    xbf   = (u16*)alloc((size_t)KT * KD * 2);
  u16*    w1t   = (u16*)alloc((size_t)KE * KD * KH * 2);   // 64 MB; dead after gemm1
  u16*    w2t   = (u16*)alloc((size_t)KE * KH * KO * 2);
  u16*    hbuf  = (u16*)alloc((size_t)2 * KT * KH * 2);
  float*  y     = (float*)w1t;   // overlay: y[2][8192][1024] fp32 = 64 MB reuses w1t

  cvt_x_k<<<(KT * KD / 4) / 256, 256, 0, stream>>>(x, xbf);
  transpose_k<<<dim3(KH / 64, KD / 64, KE), 256, 0, stream>>>(W1, w1t, KD, KH);
  transpose_k<<<dim3(KO / 64, KH / 64, KE), 256, 0, stream>>>(W2, w2t, KH, KO);
  router_k<<<KT, 64, 0, stream>>>(x, Wr, br, eidx, gpair);
  bucket_k<<<KE, 256, 0, stream>>>(eidx, cnt, tok, pos);
  offsets_k<<<1, 64, 0, stream>>>(cnt, offs);
  gemm1_k<<<dim3(KH / 128, KT / 128, KE), 256, 0, stream>>>(xbf, w1t, b1, cnt, offs, tok, hbuf);
  gemm2_k<<<dim3(2 * KO / 128, KT / 128, KE), 256, 0, stream>>>(hbuf, w2t, cnt, offs, y);
  combine_k<<<KT, 256, 0, stream>>>(y, eidx, gpair, offs, pos, b2, out);
}